// Round 1
// baseline (769.707 us; speedup 1.0000x reference)
//
#include <hip/hip_runtime.h>
#include <math.h>

#define Bsz 4
#define Tsz 5
#define Csz 64
#define Fsz 10
#define Hsz 48
#define Wsz 48
#define HWsz (Hsz*Wsz)          // 2304
#define Nsz (Tsz*HWsz)          // 11520

// ws layout (floats):
//  [0..63]                cwm   (mean_f conv1_w[:,c])
//  [64]                   cbm   (mean_f conv1_b)
//  [80 .. 80+B*N)         s     [B][N]
//  [S_G3 .. +B*F*N)       g3t   [B][F][N]
//  [S_Z .. +B*N)          z     [B][N]
//  [S_MX .. +4)           mx
//  [S_SM .. +4)           sm
#define O_CWM 0
#define O_CBM 64
#define O_S   80
#define O_G3  (O_S + Bsz*Nsz)          // 80 + 46080 = 46160
#define O_Z   (O_G3 + Bsz*Fsz*Nsz)     // 46160 + 460800 = 506960
#define O_MX  (O_Z + Bsz*Nsz)          // 553040
#define O_SM  (O_MX + 4)               // 553044
// total 553048 floats = ~2.2 MB of ws

// ---- kernel 0: fold conv1 + avgpool into a single C-vector ----
__global__ void k_prep(const float* __restrict__ cw, const float* __restrict__ cb,
                       float* __restrict__ ws) {
    int c = threadIdx.x;
    if (c < Csz) {
        float acc = 0.f;
        #pragma unroll
        for (int f = 0; f < Fsz; ++f) acc += cw[f*Csz + c];
        ws[O_CWM + c] = acc * (1.0f/Fsz);
    }
    if (c == 0) {
        float acc = 0.f;
        #pragma unroll
        for (int f = 0; f < Fsz; ++f) acc += cb[f];
        ws[O_CBM] = acc * (1.0f/Fsz);
    }
}

// ---- kernel 1: one pass over input -> s[b,n] and g3t[b][f][n] ----
__global__ __launch_bounds__(64) void k_sg3(const float* __restrict__ in,
                                            const float* __restrict__ g3w,
                                            const float* __restrict__ g3b,
                                            float* __restrict__ ws) {
    __shared__ float sw[Fsz*Csz];   // g3 weights
    __shared__ float scw[Csz + 1];  // cwm + cbm
    for (int i = threadIdx.x; i < Fsz*Csz; i += 64) sw[i] = g3w[i];
    if (threadIdx.x < Csz) scw[threadIdx.x] = ws[O_CWM + threadIdx.x];
    if (threadIdx.x == 0) scw[Csz] = ws[O_CBM];
    __syncthreads();

    const int n = blockIdx.x * 64 + threadIdx.x;   // grid.x = N/64 = 180
    const int b = blockIdx.y;
    const int t = n / HWsz;
    const int p = n - t * HWsz;

    const float* xp = in + ((size_t)(b*Tsz + t) * Csz) * HWsz + p;  // stride HWsz per c

    float accs = 0.f;
    float accf[Fsz];
    #pragma unroll
    for (int f = 0; f < Fsz; ++f) accf[f] = 0.f;

    for (int c = 0; c < Csz; ++c) {
        float xv = xp[(size_t)c * HWsz];
        accs = fmaf(xv, scw[c], accs);
        #pragma unroll
        for (int f = 0; f < Fsz; ++f) accf[f] = fmaf(xv, sw[f*Csz + c], accf[f]);
    }

    float* s   = ws + O_S;
    float* g3t = ws + O_G3;
    s[b*Nsz + n] = accs + scw[Csz];
    #pragma unroll
    for (int f = 0; f < Fsz; ++f)
        g3t[((size_t)b*Fsz + f) * Nsz + n] = accf[f] + g3b[f];
}

// ---- kernel 2: z = s @ W^T + fb  (GEMV over 530 MB W — the HBM-bound core) ----
__global__ __launch_bounds__(256) void k_gemv(const float* __restrict__ Wm,
                                              const float* __restrict__ fb,
                                              const float* __restrict__ ws) {
    const int wave = threadIdx.x >> 6;
    const int lane = threadIdx.x & 63;
    const int i = blockIdx.x * 4 + wave;          // row index, grid.x = N/4 = 2880

    const float4* wrow = (const float4*)(Wm + (size_t)i * Nsz);
    const float4* s4   = (const float4*)(ws + O_S);
    const int n4c = Nsz / 4;                      // 2880

    float a0 = 0.f, a1 = 0.f, a2 = 0.f, a3 = 0.f;
    for (int j = 0; j < Nsz/256; ++j) {           // 45 iters
        const int n4 = j*64 + lane;
        float4 w4 = wrow[n4];
        float4 sv;
        sv = s4[0*n4c + n4];
        a0 = fmaf(w4.x, sv.x, a0); a0 = fmaf(w4.y, sv.y, a0);
        a0 = fmaf(w4.z, sv.z, a0); a0 = fmaf(w4.w, sv.w, a0);
        sv = s4[1*n4c + n4];
        a1 = fmaf(w4.x, sv.x, a1); a1 = fmaf(w4.y, sv.y, a1);
        a1 = fmaf(w4.z, sv.z, a1); a1 = fmaf(w4.w, sv.w, a1);
        sv = s4[2*n4c + n4];
        a2 = fmaf(w4.x, sv.x, a2); a2 = fmaf(w4.y, sv.y, a2);
        a2 = fmaf(w4.z, sv.z, a2); a2 = fmaf(w4.w, sv.w, a2);
        sv = s4[3*n4c + n4];
        a3 = fmaf(w4.x, sv.x, a3); a3 = fmaf(w4.y, sv.y, a3);
        a3 = fmaf(w4.z, sv.z, a3); a3 = fmaf(w4.w, sv.w, a3);
    }
    #pragma unroll
    for (int off = 32; off > 0; off >>= 1) {
        a0 += __shfl_xor(a0, off, 64);
        a1 += __shfl_xor(a1, off, 64);
        a2 += __shfl_xor(a2, off, 64);
        a3 += __shfl_xor(a3, off, 64);
    }
    if (lane == 0) {
        float bias = fb[i];
        float* z = (float*)ws + O_Z;
        z[0*Nsz + i] = a0 + bias;
        z[1*Nsz + i] = a1 + bias;
        z[2*Nsz + i] = a2 + bias;
        z[3*Nsz + i] = a3 + bias;
    }
}

// ---- kernel 3a: per-batch softmax stats (max, sum exp) ----
__global__ __launch_bounds__(256) void k_stats(float* __restrict__ ws) {
    const int b = blockIdx.x;
    const float* zb = (const float*)ws + O_Z + (size_t)b * Nsz;
    const int lane = threadIdx.x & 63;
    const int wave = threadIdx.x >> 6;
    __shared__ float red[4];
    __shared__ float bcast;

    float m = -INFINITY;
    for (int i = threadIdx.x; i < Nsz; i += 256) m = fmaxf(m, zb[i]);
    #pragma unroll
    for (int off = 32; off > 0; off >>= 1) m = fmaxf(m, __shfl_xor(m, off, 64));
    if (lane == 0) red[wave] = m;
    __syncthreads();
    if (threadIdx.x == 0)
        bcast = fmaxf(fmaxf(red[0], red[1]), fmaxf(red[2], red[3]));
    __syncthreads();
    m = bcast;

    float sum = 0.f;
    for (int i = threadIdx.x; i < Nsz; i += 256) sum += expf(zb[i] - m);
    #pragma unroll
    for (int off = 32; off > 0; off >>= 1) sum += __shfl_xor(sum, off, 64);
    if (lane == 0) red[wave] = sum;
    __syncthreads();
    if (threadIdx.x == 0) {
        float* mx = ws + O_MX;
        float* sm = ws + O_SM;
        mx[b] = m;
        sm[b] = red[0] + red[1] + red[2] + red[3];
    }
}

// ---- kernel 3b: gate + scale g3, write [B,T,F,H,W] ----
__global__ __launch_bounds__(256) void k_out(const float* __restrict__ aw,
                                             const float* __restrict__ ws,
                                             float* __restrict__ out) {
    const int n = blockIdx.x * 256 + threadIdx.x;  // grid.x = N/256 = 45
    const int b = blockIdx.y;

    const float* z  = ws + O_Z;
    const float zv  = z[(size_t)b*Nsz + n];
    const float a0 = aw[0], a1 = aw[1], a2 = aw[2];
    const float mxb = ws[O_MX + b];
    const float smb = ws[O_SM + b];

    const float gate = a0 * fmaxf(zv, 0.f)
                     + a1 / (1.f + expf(-zv))
                     + a2 * expf(zv - mxb) / smb;

    const int t = n / HWsz;
    const int p = n - t * HWsz;
    const float* gp = ws + O_G3 + (size_t)b * Fsz * Nsz + n;       // [b][f][n]
    float* ob = out + ((size_t)(b*Tsz + t) * Fsz) * HWsz + p;      // [b][t][f][p]
    #pragma unroll
    for (int f = 0; f < Fsz; ++f)
        ob[(size_t)f * HWsz] = gate * gp[(size_t)f * Nsz];
}

extern "C" void kernel_launch(void* const* d_in, const int* in_sizes, int n_in,
                              void* d_out, int out_size, void* d_ws, size_t ws_size,
                              hipStream_t stream) {
    const float* input  = (const float*)d_in[0];
    // d_in[1] = input1 — unused by the reference
    const float* aw     = (const float*)d_in[2];
    const float* conv1w = (const float*)d_in[3];
    const float* conv1b = (const float*)d_in[4];
    const float* g3w    = (const float*)d_in[5];
    const float* g3b    = (const float*)d_in[6];
    const float* ffnw   = (const float*)d_in[7];
    const float* ffnb   = (const float*)d_in[8];
    float* out = (float*)d_out;
    float* ws  = (float*)d_ws;

    k_prep<<<1, 64, 0, stream>>>(conv1w, conv1b, ws);
    k_sg3<<<dim3(Nsz/64, Bsz), 64, 0, stream>>>(input, g3w, g3b, ws);
    k_gemv<<<Nsz/4, 256, 0, stream>>>(ffnw, ffnb, ws);
    k_stats<<<Bsz, 256, 0, stream>>>(ws);
    k_out<<<dim3(Nsz/256, Bsz), 256, 0, stream>>>(aw, ws, out);
}

// Round 5
// 686.187 us; speedup vs baseline: 1.1217x; 1.1217x over previous
//
#include <hip/hip_runtime.h>
#include <math.h>

#define Bsz 4
#define Tsz 5
#define Csz 64
#define Fsz 10
#define Hsz 48
#define Wsz 48
#define HWsz (Hsz*Wsz)          // 2304
#define Nsz (Tsz*HWsz)          // 11520
#define N4  (Nsz/4)             // 2880 float4 per row
#define KC4 576                 // float4 per K-chunk (2304 floats)
#define NCHUNK 5                // 5 * 2304 = 11520

typedef float float4n __attribute__((ext_vector_type(4)));

// ws layout (floats):
#define O_S   0                          // s   [B][N]
#define O_G3  (O_S + Bsz*Nsz)            // g3t [B][F][N]
#define O_Z   (O_G3 + Bsz*Fsz*Nsz)       // z   [B][N]
#define O_MX  (O_Z + Bsz*Nsz)
#define O_SM  (O_MX + 4)
// total ~553k floats = 2.2 MB

// ---- kernel 1: one pass over input -> s[b,n] and g3t[b][f][n] ----
// conv1+avgpool folded analytically: s = x . mean_f(conv1_w) + mean_f(conv1_b)
__global__ __launch_bounds__(256) void k_sg3(const float* __restrict__ in,
                                             const float* __restrict__ cw,
                                             const float* __restrict__ cb,
                                             const float* __restrict__ g3w,
                                             const float* __restrict__ g3b,
                                             float* __restrict__ ws) {
    __shared__ float sw[Fsz*Csz];   // g3 weights
    __shared__ float scw[Csz + 1];  // folded conv1 weights + bias
    if (threadIdx.x < Csz) {
        float a = 0.f;
        #pragma unroll
        for (int f = 0; f < Fsz; ++f) a += cw[f*Csz + threadIdx.x];
        scw[threadIdx.x] = a * (1.0f/Fsz);
    }
    if (threadIdx.x == 0) {
        float a = 0.f;
        #pragma unroll
        for (int f = 0; f < Fsz; ++f) a += cb[f];
        scw[Csz] = a * (1.0f/Fsz);
    }
    for (int i = threadIdx.x; i < Fsz*Csz; i += 256) sw[i] = g3w[i];
    __syncthreads();

    const int n = blockIdx.x * 256 + threadIdx.x;   // 2304 % 256 == 0 -> t uniform per block
    const int b = blockIdx.y;
    const int t = n / HWsz;
    const int p = n - t * HWsz;

    const float* xp = in + ((size_t)(b*Tsz + t) * Csz) * HWsz + p;  // stride HWsz per c

    float accs = 0.f;
    float accf[Fsz];
    #pragma unroll
    for (int f = 0; f < Fsz; ++f) accf[f] = 0.f;

    for (int c = 0; c < Csz; ++c) {
        float xv = xp[(size_t)c * HWsz];
        accs = fmaf(xv, scw[c], accs);
        #pragma unroll
        for (int f = 0; f < Fsz; ++f) accf[f] = fmaf(xv, sw[f*Csz + c], accf[f]);
    }

    float* s   = ws + O_S;
    float* g3t = ws + O_G3;
    s[b*Nsz + n] = accs + scw[Csz];
    #pragma unroll
    for (int f = 0; f < Fsz; ++f)
        g3t[((size_t)b*Fsz + f) * Nsz + n] = accf[f] + g3b[f];
}

#define DOT4(ACC, WV, SV) \
    ACC = fmaf(WV.x, SV.x, ACC); ACC = fmaf(WV.y, SV.y, ACC); \
    ACC = fmaf(WV.z, SV.z, ACC); ACC = fmaf(WV.w, SV.w, ACC)

// ---- kernel 2: z = s @ W^T + fb ----
// 16 rows/block (4 waves x 4 rows), s staged in LDS per K-chunk,
// W streamed with nontemporal loads (read-once; don't evict s from L2).
__global__ __launch_bounds__(256) void k_gemv(const float* __restrict__ Wm,
                                              const float* __restrict__ fb,
                                              float* __restrict__ ws) {
    __shared__ float4 slds[Bsz][KC4];   // 36.9 KB
    const int tid  = threadIdx.x;
    const int wave = tid >> 6;
    const int lane = tid & 63;
    const int row0 = blockIdx.x * 16 + wave * 4;

    const float4n* w0 = (const float4n*)(Wm + (size_t)(row0    ) * Nsz);
    const float4n* w1 = (const float4n*)(Wm + (size_t)(row0 + 1) * Nsz);
    const float4n* w2 = (const float4n*)(Wm + (size_t)(row0 + 2) * Nsz);
    const float4n* w3 = (const float4n*)(Wm + (size_t)(row0 + 3) * Nsz);
    const float4* s4 = (const float4*)(ws + O_S);

    float acc[4][4];   // [row][batch]
    #pragma unroll
    for (int r = 0; r < 4; ++r)
        #pragma unroll
        for (int b = 0; b < 4; ++b) acc[r][b] = 0.f;

    for (int ch = 0; ch < NCHUNK; ++ch) {
        const int c0 = ch * KC4;
        __syncthreads();
        #pragma unroll
        for (int k = 0; k < (Bsz*KC4)/256; ++k) {    // 9 iters
            const int q = k*256 + tid;
            const int b = q / KC4;
            const int j = q - b * KC4;
            slds[b][j] = s4[(size_t)b * N4 + c0 + j];
        }
        __syncthreads();

        #pragma unroll
        for (int jj = 0; jj < KC4/64; ++jj) {        // 9 iters
            const int j  = jj*64 + lane;
            const int n4 = c0 + j;
            const float4n a0 = __builtin_nontemporal_load(w0 + n4);
            const float4n a1 = __builtin_nontemporal_load(w1 + n4);
            const float4n a2 = __builtin_nontemporal_load(w2 + n4);
            const float4n a3 = __builtin_nontemporal_load(w3 + n4);
            float4 sv;
            sv = slds[0][j];
            DOT4(acc[0][0], a0, sv); DOT4(acc[1][0], a1, sv);
            DOT4(acc[2][0], a2, sv); DOT4(acc[3][0], a3, sv);
            sv = slds[1][j];
            DOT4(acc[0][1], a0, sv); DOT4(acc[1][1], a1, sv);
            DOT4(acc[2][1], a2, sv); DOT4(acc[3][1], a3, sv);
            sv = slds[2][j];
            DOT4(acc[0][2], a0, sv); DOT4(acc[1][2], a1, sv);
            DOT4(acc[2][2], a2, sv); DOT4(acc[3][2], a3, sv);
            sv = slds[3][j];
            DOT4(acc[0][3], a0, sv); DOT4(acc[1][3], a1, sv);
            DOT4(acc[2][3], a2, sv); DOT4(acc[3][3], a3, sv);
        }
    }

    #pragma unroll
    for (int r = 0; r < 4; ++r)
        #pragma unroll
        for (int b = 0; b < 4; ++b)
            #pragma unroll
            for (int off = 32; off > 0; off >>= 1)
                acc[r][b] += __shfl_xor(acc[r][b], off, 64);

    if (lane == 0) {
        float* z = ws + O_Z;
        #pragma unroll
        for (int r = 0; r < 4; ++r) {
            const float bias = fb[row0 + r];
            #pragma unroll
            for (int b = 0; b < 4; ++b)
                z[(size_t)b*Nsz + row0 + r] = acc[r][b] + bias;
        }
    }
}

// ---- kernel 3a: per-batch softmax stats (max, sum exp) ----
__global__ __launch_bounds__(256) void k_stats(float* __restrict__ ws) {
    const int b = blockIdx.x;
    const float* zb = (const float*)ws + O_Z + (size_t)b * Nsz;
    const int lane = threadIdx.x & 63;
    const int wave = threadIdx.x >> 6;
    __shared__ float red[4];
    __shared__ float bcast;

    float m = -INFINITY;
    for (int i = threadIdx.x; i < Nsz; i += 256) m = fmaxf(m, zb[i]);
    #pragma unroll
    for (int off = 32; off > 0; off >>= 1) m = fmaxf(m, __shfl_xor(m, off, 64));
    if (lane == 0) red[wave] = m;
    __syncthreads();
    if (threadIdx.x == 0)
        bcast = fmaxf(fmaxf(red[0], red[1]), fmaxf(red[2], red[3]));
    __syncthreads();
    m = bcast;

    float sum = 0.f;
    for (int i = threadIdx.x; i < Nsz; i += 256) sum += expf(zb[i] - m);
    #pragma unroll
    for (int off = 32; off > 0; off >>= 1) sum += __shfl_xor(sum, off, 64);
    if (lane == 0) red[wave] = sum;
    __syncthreads();
    if (threadIdx.x == 0) {
        ws[O_MX + b] = m;
        ws[O_SM + b] = red[0] + red[1] + red[2] + red[3];
    }
}

// ---- kernel 3b: gate + scale g3, write [B,T,F,H,W] ----
__global__ __launch_bounds__(256) void k_out(const float* __restrict__ aw,
                                             const float* __restrict__ ws,
                                             float* __restrict__ out) {
    const int n = blockIdx.x * 256 + threadIdx.x;
    const int b = blockIdx.y;

    const float zv  = ws[O_Z + (size_t)b*Nsz + n];
    const float a0 = aw[0], a1 = aw[1], a2 = aw[2];
    const float mxb = ws[O_MX + b];
    const float smb = ws[O_SM + b];

    const float gate = a0 * fmaxf(zv, 0.f)
                     + a1 / (1.f + expf(-zv))
                     + a2 * expf(zv - mxb) / smb;

    const int t = n / HWsz;
    const int p = n - t * HWsz;
    const float* gp = ws + O_G3 + (size_t)b * Fsz * Nsz + n;       // [b][f][n]
    float* ob = out + ((size_t)(b*Tsz + t) * Fsz) * HWsz + p;      // [b][t][f][p]
    #pragma unroll
    for (int f = 0; f < Fsz; ++f)
        ob[(size_t)f * HWsz] = gate * gp[(size_t)f * Nsz];
}

extern "C" void kernel_launch(void* const* d_in, const int* in_sizes, int n_in,
                              void* d_out, int out_size, void* d_ws, size_t ws_size,
                              hipStream_t stream) {
    const float* input  = (const float*)d_in[0];
    // d_in[1] = input1 — unused by the reference
    const float* aw     = (const float*)d_in[2];
    const float* conv1w = (const float*)d_in[3];
    const float* conv1b = (const float*)d_in[4];
    const float* g3w    = (const float*)d_in[5];
    const float* g3b    = (const float*)d_in[6];
    const float* ffnw   = (const float*)d_in[7];
    const float* ffnb   = (const float*)d_in[8];
    float* out = (float*)d_out;
    float* ws  = (float*)d_ws;

    k_sg3  <<<dim3(Nsz/256, Bsz), 256, 0, stream>>>(input, conv1w, conv1b, g3w, g3b, ws);
    k_gemv <<<Nsz/16, 256, 0, stream>>>(ffnw, ffnb, ws);
    k_stats<<<Bsz, 256, 0, stream>>>(ws);
    k_out  <<<dim3(Nsz/256, Bsz), 256, 0, stream>>>(aw, ws, out);
}